// Round 7
// baseline (134.349 us; speedup 1.0000x reference)
//
#include <hip/hip_runtime.h>

// WaveletFeatureExtractor: db4 wavedec (5 levels, symmetric pad) -> adaptive pool 128
// -> per-level 128x128 MLP (ReLU) -> fused 640->512 MLP (ReLU).
//
// Round 7: dwt restructured for latency-bound regime (round 6 showed conflicts
// fixed but time flat: 2 blocks/CU x 6 dependent phases = nothing to hide LDS
// latency under).
//  - 8 blocks per row, each computes the full cascade on a 1/8 chunk with halo
//    recompute (+13% FLOPs). ~11 KB LDS/block -> 8 blocks/CU resident.
//  - Block b exclusively owns pooled buckets [16b,16b+16) of every band; chunk
//    ranges derived backward (pool range union expanded child need). No atomics.
//  - mlp: 1024 thr, f16 weights pre-packed once per launch into d_ws.

#define BATCH   2048
#define SIGLEN  16384
#define N1      8195
#define N2      4101
#define N3      2054
#define N4      1030
#define N5      518
#define POOLP   128
#define COMB    640
#define OUTD    512
#define NB      8      // blocks per row
#define NTHR    256

#define SWZ(i) ((i) ^ ((((i) >> 5) & 7) << 2))

__device__ constexpr float LO[8] = {
     0.2303778133088965f,   0.7148465705529157f,   0.6308807679298589f,
    -0.027983769416859854f, -0.18703481171909309f,  0.030841381835560764f,
     0.0328830116668852f,  -0.010597401785069032f };
__device__ constexpr float HI[8] = {
    -0.010597401785069032f, -0.0328830116668852f,   0.030841381835560764f,
     0.18703481171909309f,  -0.027983769416859854f, -0.6308807679298589f,
     0.7148465705529157f,  -0.2303778133088965f };

__device__ __forceinline__ int symfold(int idx, int n) {
    idx = (idx < 0) ? (-1 - idx) : idx;
    idx = (idx >= n) ? (2 * n - 1 - idx) : idx;
    return idx;
}

// DWT of one level over a chunk. src holds band values for abs indices [ss,se)
// at LDS slot SWZ(j - bsrc), bsrc = (ss&~3)-8 (8-slot pad below). Outputs abs
// [s,e) -> dstA/dstD at slot SWZ(j - bdst). Nsrc = source band length (fold).
__device__ __forceinline__ void dwt_chunk(const float* __restrict__ src,
                                          int ss, int se, int bsrc, int Nsrc,
                                          float* __restrict__ dstA,
                                          float* __restrict__ dstD,
                                          int s, int e, int bdst, int tid) {
    for (int j0 = (s & ~3) + tid * 4; j0 < e; j0 += NTHR * 4) {
        const int rb = 2 * j0 - 8;
        if ((rb >= ss) && (2 * j0 + 7 <= se - 1) && (j0 + 4 <= e)) {
            const int lrb = rb - bsrc;
            const float4 v0 = *reinterpret_cast<const float4*>(src + SWZ(lrb));
            const float4 v1 = *reinterpret_cast<const float4*>(src + SWZ(lrb + 4));
            const float4 v2 = *reinterpret_cast<const float4*>(src + SWZ(lrb + 8));
            const float4 v3 = *reinterpret_cast<const float4*>(src + SWZ(lrb + 12));
            float w[16];
            w[0]=v0.x;  w[1]=v0.y;  w[2]=v0.z;  w[3]=v0.w;
            w[4]=v1.x;  w[5]=v1.y;  w[6]=v1.z;  w[7]=v1.w;
            w[8]=v2.x;  w[9]=v2.y;  w[10]=v2.z; w[11]=v2.w;
            w[12]=v3.x; w[13]=v3.y; w[14]=v3.z; w[15]=v3.w;
            float a[4], d[4];
#pragma unroll
            for (int k = 0; k < 4; ++k) {
                float aa = 0.f, dd = 0.f;
#pragma unroll
                for (int t = 0; t < 8; ++t) {
                    const float v = w[2 + 2 * k + t];
                    aa = fmaf(v, LO[t], aa);
                    dd = fmaf(v, HI[t], dd);
                }
                a[k] = aa; d[k] = dd;
            }
            const int ds = j0 - bdst;
            *reinterpret_cast<float4*>(dstA + SWZ(ds)) = make_float4(a[0], a[1], a[2], a[3]);
            *reinterpret_cast<float4*>(dstD + SWZ(ds)) = make_float4(d[0], d[1], d[2], d[3]);
        } else {
            for (int k = 0; k < 4; ++k) {
                const int j = j0 + k;
                if (j < s || j >= e) continue;
                float aa = 0.f, dd = 0.f;
#pragma unroll
                for (int t = 0; t < 8; ++t) {
                    const int idx = symfold(2 * j - 6 + t, Nsrc);
                    const float v = src[SWZ(idx - bsrc)];
                    aa = fmaf(v, LO[t], aa);
                    dd = fmaf(v, HI[t], dd);
                }
                dstA[SWZ(j - bdst)] = aa;
                dstD[SWZ(j - bdst)] = dd;
            }
        }
    }
}

// Level 1 from global x (low-pass only; cD1 is dead in the reference forward).
__device__ __forceinline__ void dwt_l1(const float* __restrict__ xr,
                                       float* __restrict__ dstA,
                                       int s, int e, int bdst, int tid) {
    for (int j0 = (s & ~3) + tid * 4; j0 < e; j0 += NTHR * 4) {
        const int rb = 2 * j0 - 8;
        if ((rb >= 0) && (2 * j0 + 7 <= SIGLEN - 1) && (j0 + 4 <= e)) {
            const float4* s4 = reinterpret_cast<const float4*>(xr + rb);
            const float4 v0 = s4[0], v1 = s4[1], v2 = s4[2], v3 = s4[3];
            float w[16];
            w[0]=v0.x;  w[1]=v0.y;  w[2]=v0.z;  w[3]=v0.w;
            w[4]=v1.x;  w[5]=v1.y;  w[6]=v1.z;  w[7]=v1.w;
            w[8]=v2.x;  w[9]=v2.y;  w[10]=v2.z; w[11]=v2.w;
            w[12]=v3.x; w[13]=v3.y; w[14]=v3.z; w[15]=v3.w;
            float a[4];
#pragma unroll
            for (int k = 0; k < 4; ++k) {
                float aa = 0.f;
#pragma unroll
                for (int t = 0; t < 8; ++t) aa = fmaf(w[2 + 2 * k + t], LO[t], aa);
                a[k] = aa;
            }
            *reinterpret_cast<float4*>(dstA + SWZ(j0 - bdst)) = make_float4(a[0], a[1], a[2], a[3]);
        } else {
            for (int k = 0; k < 4; ++k) {
                const int j = j0 + k;
                if (j < s || j >= e) continue;
                float aa = 0.f;
#pragma unroll
                for (int t = 0; t < 8; ++t) {
                    const int idx = symfold(2 * j - 6 + t, SIGLEN);
                    aa = fmaf(xr[idx], LO[t], aa);
                }
                dstA[SWZ(j - bdst)] = aa;
            }
        }
    }
}

// Pool the block's 16 owned buckets of one band. 16 threads/bucket, stride-16
// partials + 4x shfl_xor; lane sub==0 writes the mean. Exclusive -> no atomics.
__device__ __forceinline__ void pool_chunk(const float* __restrict__ buf, int base, int N,
                                           int p0, float* __restrict__ dst, int tid) {
    const int p = p0 + (tid >> 4), sub = tid & 15;
    const int s = (p * N) >> 7;
    const int e = ((p + 1) * N + 127) >> 7;
    float acc = 0.f;
    for (int t = s + sub; t < e; t += 16) acc += buf[SWZ(t - base)];
    acc += __shfl_xor(acc, 1);
    acc += __shfl_xor(acc, 2);
    acc += __shfl_xor(acc, 4);
    acc += __shfl_xor(acc, 8);
    if (sub == 0) dst[p] = acc / (float)(e - s);
}

__global__ __launch_bounds__(NTHR, 8) void dwt_pool_kernel(const float* __restrict__ x,
                                                           float* __restrict__ pooled) {
    __shared__ __align__(16) float A[1280];    // cA1 / cA3 / cA5 chunks
    __shared__ __align__(16) float Bb[704];    // cA2 / cA4 chunks
    __shared__ __align__(16) float D1[704];    // cD2 / cD4 chunks
    __shared__ __align__(16) float D2[384];    // cD3 / cD5 chunks

    const int tid = threadIdx.x;
    const int bx  = blockIdx.x;
    const int row = bx >> 3;
    const int b   = bx & 7;
    const int p0  = b << 4;                    // owned buckets [p0, p0+16)

    const float* __restrict__ xr = x + (size_t)row * SIGLEN;
    float* __restrict__ pr = pooled + (size_t)row * COMB;

    // Owned-bucket element ranges per band (torch: [p*N>>7, ((p+1)*N+127)>>7))
    const int sP5 = (p0 * N5) >> 7, eP5 = ((p0 + 16) * N5 + 127) >> 7;
    const int sP4 = (p0 * N4) >> 7, eP4 = ((p0 + 16) * N4 + 127) >> 7;
    const int sP3 = (p0 * N3) >> 7, eP3 = ((p0 + 16) * N3 + 127) >> 7;
    const int sP2 = (p0 * N2) >> 7, eP2 = ((p0 + 16) * N2 + 127) >> 7;

    // Chunk (need) ranges, derived backward: pool range  U  expand(child need)
    const int s5 = sP5, e5 = eP5;
    int s4 = min(sP4, 2 * s5 - 6); s4 = max(s4, 0);
    int e4 = max(eP4, 2 * e5);     e4 = min(e4, N4);
    int s3 = min(sP3, 2 * s4 - 6); s3 = max(s3, 0);
    int e3 = max(eP3, 2 * e4);     e3 = min(e3, N3);
    int s2 = min(sP2, 2 * s3 - 6); s2 = max(s2, 0);
    int e2 = max(eP2, 2 * e3);     e2 = min(e2, N2);
    int s1 = max(2 * s2 - 6, 0);
    int e1 = min(2 * e2, N1);

    const int b1 = (s1 & ~3) - 8, b2 = (s2 & ~3) - 8, b3 = (s3 & ~3) - 8;
    const int b4 = (s4 & ~3) - 8, b5 = (s5 & ~3) - 8;

    // P0: level 1 global -> A
    dwt_l1(xr, A, s1, e1, b1, tid);
    __syncthreads();
    // P1: level 2: A -> Bb(cA2), D1(cD2)
    dwt_chunk(A, s1, e1, b1, N1, Bb, D1, s2, e2, b2, tid);
    __syncthreads();
    // P2: level 3: Bb -> A(cA3), D2(cD3)   || pool cD2 -> slot 4
    dwt_chunk(Bb, s2, e2, b2, N2, A, D2, s3, e3, b3, tid);
    pool_chunk(D1, b2, N2, p0, pr + 4 * POOLP, tid);
    __syncthreads();
    // P3: level 4: A -> Bb(cA4), D1(cD4)   || pool cD3 -> slot 3
    dwt_chunk(A, s3, e3, b3, N3, Bb, D1, s4, e4, b4, tid);
    pool_chunk(D2, b3, N3, p0, pr + 3 * POOLP, tid);
    __syncthreads();
    // P4: level 5: Bb -> A(cA5), D2(cD5)   || pool cD4 -> slot 2
    dwt_chunk(Bb, s4, e4, b4, N4, A, D2, s5, e5, b5, tid);
    pool_chunk(D1, b4, N4, p0, pr + 2 * POOLP, tid);
    __syncthreads();
    // P5: pool cA5 -> slot 0, cD5 -> slot 1
    pool_chunk(A,  b5, N5, p0, pr + 0 * POOLP, tid);
    pool_chunk(D2, b5, N5, p0, pr + 1 * POOLP, tid);
}

// ---------------- MLP ----------------

typedef __fp16 h2 __attribute__((ext_vector_type(2)));

#define LW_PAIRS (5 * 128 * 128 / 2)   // 40960
#define FW_PAIRS (512 * 640 / 2)       // 163840

__global__ __launch_bounds__(256) void pack_w(const float* __restrict__ lw,
                                              const float* __restrict__ fw,
                                              h2* __restrict__ lwh,
                                              h2* __restrict__ fwh) {
    const int i = blockIdx.x * 256 + threadIdx.x;
    if (i < LW_PAIRS) {
        const float2 v = reinterpret_cast<const float2*>(lw)[i];
        lwh[i] = __builtin_amdgcn_cvt_pkrtz(v.x, v.y);
    } else if (i < LW_PAIRS + FW_PAIRS) {
        const float2 v = reinterpret_cast<const float2*>(fw)[i - LW_PAIRS];
        fwh[i - LW_PAIRS] = __builtin_amdgcn_cvt_pkrtz(v.x, v.y);
    }
}

__global__ __launch_bounds__(1024, 4) void mlp_kernel(const float* __restrict__ pooled,
                                                      const h2* __restrict__ lwh,  // [640][64]
                                                      const float* __restrict__ lb,
                                                      const h2* __restrict__ fwh,  // [512][320]
                                                      const float* __restrict__ fb,
                                                      float* __restrict__ out) {
    __shared__ h2 sph[8][COMB / 2];  // pooled tile f16  (8 x 320)
    __shared__ h2 sch[8][COMB / 2];  // comb tile f16

    const int tid = threadIdx.x;
    const int r0 = blockIdx.x * 8;

    const float2* __restrict__ srcp = reinterpret_cast<const float2*>(pooled + (size_t)r0 * COMB);
    for (int i = tid; i < 8 * (COMB / 2); i += 1024) {
        const float2 v = srcp[i];
        (&sph[0][0])[i] = __builtin_amdgcn_cvt_pkrtz(v.x, v.y);
    }
    __syncthreads();

    // Level nets: idx -> (c, row-half); 4 rows per thread
    for (int idx = tid; idx < COMB * 2; idx += 1024) {
        const int c = idx >> 1, rh = (idx & 1) * 4;
        const h2* __restrict__ w = lwh + (size_t)c * 64;
        const int lb2 = (c >> 7) * 64;
        const float bias = lb[c];
        float acc[4] = {bias, bias, bias, bias};
        for (int t2 = 0; t2 < 64; t2 += 4) {
            const float4 wraw = *reinterpret_cast<const float4*>(w + t2);
            const h2 w0 = __builtin_bit_cast(h2, wraw.x);
            const h2 w1 = __builtin_bit_cast(h2, wraw.y);
            const h2 w2 = __builtin_bit_cast(h2, wraw.z);
            const h2 w3 = __builtin_bit_cast(h2, wraw.w);
#pragma unroll
            for (int r = 0; r < 4; ++r) {
                const float4 praw = *reinterpret_cast<const float4*>(&sph[rh + r][lb2 + t2]);
                acc[r] = __builtin_amdgcn_fdot2(__builtin_bit_cast(h2, praw.x), w0, acc[r], false);
                acc[r] = __builtin_amdgcn_fdot2(__builtin_bit_cast(h2, praw.y), w1, acc[r], false);
                acc[r] = __builtin_amdgcn_fdot2(__builtin_bit_cast(h2, praw.z), w2, acc[r], false);
                acc[r] = __builtin_amdgcn_fdot2(__builtin_bit_cast(h2, praw.w), w3, acc[r], false);
            }
        }
        __fp16* __restrict__ schf = reinterpret_cast<__fp16*>(&sch[0][0]);
#pragma unroll
        for (int r = 0; r < 4; ++r) schf[(rh + r) * COMB + c] = (__fp16)fmaxf(acc[r], 0.f);
    }
    __syncthreads();

    // Fusion: tid -> (c, row-half); 4 rows per thread; 1024 = 512 c x 2 halves
    {
        const int c = tid >> 1, rh = (tid & 1) * 4;
        const h2* __restrict__ w = fwh + (size_t)c * (COMB / 2);
        const float bias = fb[c];
        float acc[4] = {bias, bias, bias, bias};
        for (int t2 = 0; t2 < COMB / 2; t2 += 4) {
            const float4 wraw = *reinterpret_cast<const float4*>(w + t2);
            const h2 w0 = __builtin_bit_cast(h2, wraw.x);
            const h2 w1 = __builtin_bit_cast(h2, wraw.y);
            const h2 w2 = __builtin_bit_cast(h2, wraw.z);
            const h2 w3 = __builtin_bit_cast(h2, wraw.w);
#pragma unroll
            for (int r = 0; r < 4; ++r) {
                const float4 craw = *reinterpret_cast<const float4*>(&sch[rh + r][t2]);
                acc[r] = __builtin_amdgcn_fdot2(__builtin_bit_cast(h2, craw.x), w0, acc[r], false);
                acc[r] = __builtin_amdgcn_fdot2(__builtin_bit_cast(h2, craw.y), w1, acc[r], false);
                acc[r] = __builtin_amdgcn_fdot2(__builtin_bit_cast(h2, craw.z), w2, acc[r], false);
                acc[r] = __builtin_amdgcn_fdot2(__builtin_bit_cast(h2, craw.w), w3, acc[r], false);
            }
        }
#pragma unroll
        for (int r = 0; r < 4; ++r) {
            out[(size_t)(r0 + rh + r) * OUTD + c] = fmaxf(acc[r], 0.f);
        }
    }
}

// Fallback mlp (round 6): in-kernel weight cvt, 512 thr — used if d_ws too small
__global__ __launch_bounds__(512) void mlp_kernel_fb(const float* __restrict__ pooled,
                                                     const float* __restrict__ lw,
                                                     const float* __restrict__ lb,
                                                     const float* __restrict__ fw,
                                                     const float* __restrict__ fb,
                                                     float* __restrict__ out) {
    __shared__ h2 sph[8][COMB / 2];
    __shared__ h2 sch[8][COMB / 2];
    const int tid = threadIdx.x;
    const int r0 = blockIdx.x * 8;
    const float2* __restrict__ srcp = reinterpret_cast<const float2*>(pooled + (size_t)r0 * COMB);
    for (int i = tid; i < 8 * (COMB / 2); i += 512) {
        const float2 v = srcp[i];
        (&sph[0][0])[i] = __builtin_amdgcn_cvt_pkrtz(v.x, v.y);
    }
    __syncthreads();
    for (int c = tid; c < COMB; c += 512) {
        const float* __restrict__ w = lw + (size_t)c * POOLP;
        const int lb2 = (c >> 7) * (POOLP / 2);
        const float bias = lb[c];
        float acc[8];
#pragma unroll
        for (int r = 0; r < 8; ++r) acc[r] = bias;
        for (int t2 = 0; t2 < POOLP / 2; t2 += 4) {
            const float4 wa = *reinterpret_cast<const float4*>(w + t2 * 2);
            const float4 wb = *reinterpret_cast<const float4*>(w + t2 * 2 + 4);
            const h2 w0 = __builtin_amdgcn_cvt_pkrtz(wa.x, wa.y);
            const h2 w1 = __builtin_amdgcn_cvt_pkrtz(wa.z, wa.w);
            const h2 w2 = __builtin_amdgcn_cvt_pkrtz(wb.x, wb.y);
            const h2 w3 = __builtin_amdgcn_cvt_pkrtz(wb.z, wb.w);
#pragma unroll
            for (int r = 0; r < 8; ++r) {
                const float4 raw = *reinterpret_cast<const float4*>(&sph[r][lb2 + t2]);
                acc[r] = __builtin_amdgcn_fdot2(__builtin_bit_cast(h2, raw.x), w0, acc[r], false);
                acc[r] = __builtin_amdgcn_fdot2(__builtin_bit_cast(h2, raw.y), w1, acc[r], false);
                acc[r] = __builtin_amdgcn_fdot2(__builtin_bit_cast(h2, raw.z), w2, acc[r], false);
                acc[r] = __builtin_amdgcn_fdot2(__builtin_bit_cast(h2, raw.w), w3, acc[r], false);
            }
        }
        __fp16* __restrict__ schf = reinterpret_cast<__fp16*>(&sch[0][0]);
#pragma unroll
        for (int r = 0; r < 8; ++r) schf[r * COMB + c] = (__fp16)fmaxf(acc[r], 0.f);
    }
    __syncthreads();
    {
        const int j = tid;
        const float* __restrict__ w = fw + (size_t)j * COMB;
        const float bias = fb[j];
        float acc[8];
#pragma unroll
        for (int r = 0; r < 8; ++r) acc[r] = bias;
        for (int t2 = 0; t2 < COMB / 2; t2 += 4) {
            const float4 wa = *reinterpret_cast<const float4*>(w + t2 * 2);
            const float4 wb = *reinterpret_cast<const float4*>(w + t2 * 2 + 4);
            const h2 w0 = __builtin_amdgcn_cvt_pkrtz(wa.x, wa.y);
            const h2 w1 = __builtin_amdgcn_cvt_pkrtz(wa.z, wa.w);
            const h2 w2 = __builtin_amdgcn_cvt_pkrtz(wb.x, wb.y);
            const h2 w3 = __builtin_amdgcn_cvt_pkrtz(wb.z, wb.w);
#pragma unroll
            for (int r = 0; r < 8; ++r) {
                const float4 raw = *reinterpret_cast<const float4*>(&sch[r][t2]);
                acc[r] = __builtin_amdgcn_fdot2(__builtin_bit_cast(h2, raw.x), w0, acc[r], false);
                acc[r] = __builtin_amdgcn_fdot2(__builtin_bit_cast(h2, raw.y), w1, acc[r], false);
                acc[r] = __builtin_amdgcn_fdot2(__builtin_bit_cast(h2, raw.z), w2, acc[r], false);
                acc[r] = __builtin_amdgcn_fdot2(__builtin_bit_cast(h2, raw.w), w3, acc[r], false);
            }
        }
#pragma unroll
        for (int r = 0; r < 8; ++r) {
            out[(size_t)(r0 + r) * OUTD + j] = fmaxf(acc[r], 0.f);
        }
    }
}

extern "C" void kernel_launch(void* const* d_in, const int* in_sizes, int n_in,
                              void* d_out, int out_size, void* d_ws, size_t ws_size,
                              hipStream_t stream) {
    const float* x  = (const float*)d_in[0];
    const float* lw = (const float*)d_in[1];
    const float* lb = (const float*)d_in[2];
    const float* fw = (const float*)d_in[3];
    const float* fb = (const float*)d_in[4];
    float* out = (float*)d_out;

    float* pooled = (float*)d_ws;                       // [2048][640] f32
    const size_t POOLED_B = (size_t)BATCH * COMB * 4;   // 5,242,880
    const size_t NEEDED   = POOLED_B + (size_t)(LW_PAIRS + FW_PAIRS) * 4;

    dwt_pool_kernel<<<BATCH * NB, NTHR, 0, stream>>>(x, pooled);

    if (ws_size >= NEEDED) {
        h2* lwh = (h2*)((char*)d_ws + POOLED_B);
        h2* fwh = (h2*)((char*)d_ws + POOLED_B + (size_t)LW_PAIRS * 4);
        pack_w<<<(LW_PAIRS + FW_PAIRS + 255) / 256, 256, 0, stream>>>(lw, fw, lwh, fwh);
        mlp_kernel<<<BATCH / 8, 1024, 0, stream>>>(pooled, lwh, lb, fwh, fb, out);
    } else {
        mlp_kernel_fb<<<BATCH / 8, 512, 0, stream>>>(pooled, lw, lb, fw, fb, out);
    }
}

// Round 8
// 120.936 us; speedup vs baseline: 1.1109x; 1.1109x over previous
//
#include <hip/hip_runtime.h>

// WaveletFeatureExtractor: db4 wavedec (5 levels, symmetric pad) -> adaptive pool 128
// -> per-level 128x128 MLP (ReLU) -> fused 640->512 MLP (ReLU).
//
// Round 8: round-7 structure (8 blocks/row, halo recompute, exclusive bucket
// ownership) with the VALU bloat removed:
//  - lb(256,4) instead of (256,8): round 7's pledge forced VGPR=28 and ~2.8x
//    instruction inflation (round-4 mistake repeated).
//  - per-block body templated on chunk id B: all chunk ranges / LDS bases /
//    trip counts / owned buckets are constexpr -> bounds checks fold, SWZ
//    folds, loops unroll. Block-uniform switch on blockIdx.x&7.

#define BATCH   2048
#define SIGLEN  16384
#define N1      8195
#define N2      4101
#define N3      2054
#define N4      1030
#define N5      518
#define POOLP   128
#define COMB    640
#define OUTD    512
#define NB      8
#define NTHR    256

#define SWZ(i) ((i) ^ ((((i) >> 5) & 7) << 2))

__device__ constexpr float LO[8] = {
     0.2303778133088965f,   0.7148465705529157f,   0.6308807679298589f,
    -0.027983769416859854f, -0.18703481171909309f,  0.030841381835560764f,
     0.0328830116668852f,  -0.010597401785069032f };
__device__ constexpr float HI[8] = {
    -0.010597401785069032f, -0.0328830116668852f,   0.030841381835560764f,
     0.18703481171909309f,  -0.027983769416859854f, -0.6308807679298589f,
     0.7148465705529157f,  -0.2303778133088965f };

__device__ __forceinline__ int symfold(int idx, int n) {
    idx = (idx < 0) ? (-1 - idx) : idx;
    idx = (idx >= n) ? (2 * n - 1 - idx) : idx;
    return idx;
}

constexpr int cmin(int a, int b) { return a < b ? a : b; }
constexpr int cmax(int a, int b) { return a > b ? a : b; }

// One DWT level over a chunk; all geometry compile-time.
// src holds abs indices [SS,SE) at slot SWZ(j-BSRC); outputs abs [S,E) to
// dstA/dstD at slot SWZ(j-BDST).
template<int SS, int SE, int BSRC, int NSRC, int S, int E, int BDST>
__device__ __forceinline__ void dwt_chunk(const float* __restrict__ src,
                                          float* __restrict__ dstA,
                                          float* __restrict__ dstD,
                                          int tid) {
    for (int j0 = (S & ~3) + tid * 4; j0 < E; j0 += NTHR * 4) {
        const int rb = 2 * j0 - 8;
        if ((rb >= SS) && (2 * j0 + 7 <= SE - 1) && (j0 + 4 <= E)) {
            const int lrb = rb - BSRC;
            const float4 v0 = *reinterpret_cast<const float4*>(src + SWZ(lrb));
            const float4 v1 = *reinterpret_cast<const float4*>(src + SWZ(lrb + 4));
            const float4 v2 = *reinterpret_cast<const float4*>(src + SWZ(lrb + 8));
            const float4 v3 = *reinterpret_cast<const float4*>(src + SWZ(lrb + 12));
            float w[16];
            w[0]=v0.x;  w[1]=v0.y;  w[2]=v0.z;  w[3]=v0.w;
            w[4]=v1.x;  w[5]=v1.y;  w[6]=v1.z;  w[7]=v1.w;
            w[8]=v2.x;  w[9]=v2.y;  w[10]=v2.z; w[11]=v2.w;
            w[12]=v3.x; w[13]=v3.y; w[14]=v3.z; w[15]=v3.w;
            float a[4], d[4];
#pragma unroll
            for (int k = 0; k < 4; ++k) {
                float aa = 0.f, dd = 0.f;
#pragma unroll
                for (int t = 0; t < 8; ++t) {
                    const float v = w[2 + 2 * k + t];
                    aa = fmaf(v, LO[t], aa);
                    dd = fmaf(v, HI[t], dd);
                }
                a[k] = aa; d[k] = dd;
            }
            const int ds = j0 - BDST;
            *reinterpret_cast<float4*>(dstA + SWZ(ds)) = make_float4(a[0], a[1], a[2], a[3]);
            *reinterpret_cast<float4*>(dstD + SWZ(ds)) = make_float4(d[0], d[1], d[2], d[3]);
        } else {
            for (int k = 0; k < 4; ++k) {
                const int j = j0 + k;
                if (j < S || j >= E) continue;
                float aa = 0.f, dd = 0.f;
#pragma unroll
                for (int t = 0; t < 8; ++t) {
                    const int idx = symfold(2 * j - 6 + t, NSRC);
                    const float v = src[SWZ(idx - BSRC)];
                    aa = fmaf(v, LO[t], aa);
                    dd = fmaf(v, HI[t], dd);
                }
                dstA[SWZ(j - BDST)] = aa;
                dstD[SWZ(j - BDST)] = dd;
            }
        }
    }
}

// Level 1 from global x (low-pass only; cD1 is dead in the reference forward).
template<int S, int E, int BDST>
__device__ __forceinline__ void dwt_l1(const float* __restrict__ xr,
                                       float* __restrict__ dstA, int tid) {
    for (int j0 = (S & ~3) + tid * 4; j0 < E; j0 += NTHR * 4) {
        const int rb = 2 * j0 - 8;
        if ((rb >= 0) && (2 * j0 + 7 <= SIGLEN - 1) && (j0 + 4 <= E)) {
            const float4* s4 = reinterpret_cast<const float4*>(xr + rb);
            const float4 v0 = s4[0], v1 = s4[1], v2 = s4[2], v3 = s4[3];
            float w[16];
            w[0]=v0.x;  w[1]=v0.y;  w[2]=v0.z;  w[3]=v0.w;
            w[4]=v1.x;  w[5]=v1.y;  w[6]=v1.z;  w[7]=v1.w;
            w[8]=v2.x;  w[9]=v2.y;  w[10]=v2.z; w[11]=v2.w;
            w[12]=v3.x; w[13]=v3.y; w[14]=v3.z; w[15]=v3.w;
            float a[4];
#pragma unroll
            for (int k = 0; k < 4; ++k) {
                float aa = 0.f;
#pragma unroll
                for (int t = 0; t < 8; ++t) aa = fmaf(w[2 + 2 * k + t], LO[t], aa);
                a[k] = aa;
            }
            *reinterpret_cast<float4*>(dstA + SWZ(j0 - BDST)) = make_float4(a[0], a[1], a[2], a[3]);
        } else {
            for (int k = 0; k < 4; ++k) {
                const int j = j0 + k;
                if (j < S || j >= E) continue;
                float aa = 0.f;
#pragma unroll
                for (int t = 0; t < 8; ++t) {
                    const int idx = symfold(2 * j - 6 + t, SIGLEN);
                    aa = fmaf(xr[idx], LO[t], aa);
                }
                dstA[SWZ(j - BDST)] = aa;
            }
        }
    }
}

// Pool the block's 16 owned buckets of one band; 16 threads/bucket.
template<int N, int BASE, int P0>
__device__ __forceinline__ void pool_chunk(const float* __restrict__ buf,
                                           float* __restrict__ dst, int tid) {
    const int p = P0 + (tid >> 4), sub = tid & 15;
    const int s = (p * N) >> 7;
    const int e = ((p + 1) * N + 127) >> 7;
    float acc = 0.f;
    for (int t = s + sub; t < e; t += 16) acc += buf[SWZ(t - BASE)];
    acc += __shfl_xor(acc, 1);
    acc += __shfl_xor(acc, 2);
    acc += __shfl_xor(acc, 4);
    acc += __shfl_xor(acc, 8);
    if (sub == 0) dst[p] = acc / (float)(e - s);
}

template<int B>
__device__ __forceinline__ void dwt_body(const float* __restrict__ xr,
                                         float* __restrict__ pr,
                                         float* __restrict__ A,
                                         float* __restrict__ Bb,
                                         float* __restrict__ D1,
                                         float* __restrict__ D2,
                                         int tid) {
    constexpr int p0 = B * 16;
    // owned-bucket element ranges
    constexpr int sP5 = (p0 * N5) >> 7, eP5 = ((p0 + 16) * N5 + 127) >> 7;
    constexpr int sP4 = (p0 * N4) >> 7, eP4 = ((p0 + 16) * N4 + 127) >> 7;
    constexpr int sP3 = (p0 * N3) >> 7, eP3 = ((p0 + 16) * N3 + 127) >> 7;
    constexpr int sP2 = (p0 * N2) >> 7, eP2 = ((p0 + 16) * N2 + 127) >> 7;
    // chunk ranges backward: pool range U expand(child need)
    constexpr int s5 = sP5, e5 = eP5;
    constexpr int s4 = cmax(cmin(sP4, 2 * s5 - 6), 0);
    constexpr int e4 = cmin(cmax(eP4, 2 * e5), N4);
    constexpr int s3 = cmax(cmin(sP3, 2 * s4 - 6), 0);
    constexpr int e3 = cmin(cmax(eP3, 2 * e4), N3);
    constexpr int s2 = cmax(cmin(sP2, 2 * s3 - 6), 0);
    constexpr int e2 = cmin(cmax(eP2, 2 * e3), N2);
    constexpr int s1 = cmax(2 * s2 - 6, 0);
    constexpr int e1 = cmin(2 * e2, N1);
    constexpr int b1 = (s1 & ~3) - 8, b2 = (s2 & ~3) - 8, b3 = (s3 & ~3) - 8;
    constexpr int b4 = (s4 & ~3) - 8, b5 = (s5 & ~3) - 8;

    dwt_l1<s1, e1, b1>(xr, A, tid);
    __syncthreads();
    dwt_chunk<s1, e1, b1, N1, s2, e2, b2>(A, Bb, D1, tid);
    __syncthreads();
    dwt_chunk<s2, e2, b2, N2, s3, e3, b3>(Bb, A, D2, tid);
    pool_chunk<N2, b2, p0>(D1, pr + 4 * POOLP, tid);
    __syncthreads();
    dwt_chunk<s3, e3, b3, N3, s4, e4, b4>(A, Bb, D1, tid);
    pool_chunk<N3, b3, p0>(D2, pr + 3 * POOLP, tid);
    __syncthreads();
    dwt_chunk<s4, e4, b4, N4, s5, e5, b5>(Bb, A, D2, tid);
    pool_chunk<N4, b4, p0>(D1, pr + 2 * POOLP, tid);
    __syncthreads();
    pool_chunk<N5, b5, p0>(A,  pr + 0 * POOLP, tid);
    pool_chunk<N5, b5, p0>(D2, pr + 1 * POOLP, tid);
}

__global__ __launch_bounds__(NTHR, 4) void dwt_pool_kernel(const float* __restrict__ x,
                                                           float* __restrict__ pooled) {
    __shared__ __align__(16) float A[1280];
    __shared__ __align__(16) float Bb[704];
    __shared__ __align__(16) float D1[704];
    __shared__ __align__(16) float D2[384];

    const int tid = threadIdx.x;
    const int row = blockIdx.x >> 3;
    const float* __restrict__ xr = x + (size_t)row * SIGLEN;
    float* __restrict__ pr = pooled + (size_t)row * COMB;

    switch (blockIdx.x & 7) {
        case 0: dwt_body<0>(xr, pr, A, Bb, D1, D2, tid); break;
        case 1: dwt_body<1>(xr, pr, A, Bb, D1, D2, tid); break;
        case 2: dwt_body<2>(xr, pr, A, Bb, D1, D2, tid); break;
        case 3: dwt_body<3>(xr, pr, A, Bb, D1, D2, tid); break;
        case 4: dwt_body<4>(xr, pr, A, Bb, D1, D2, tid); break;
        case 5: dwt_body<5>(xr, pr, A, Bb, D1, D2, tid); break;
        case 6: dwt_body<6>(xr, pr, A, Bb, D1, D2, tid); break;
        default: dwt_body<7>(xr, pr, A, Bb, D1, D2, tid); break;
    }
}

// ---------------- MLP (unchanged from round 7) ----------------

typedef __fp16 h2 __attribute__((ext_vector_type(2)));

#define LW_PAIRS (5 * 128 * 128 / 2)
#define FW_PAIRS (512 * 640 / 2)

__global__ __launch_bounds__(256) void pack_w(const float* __restrict__ lw,
                                              const float* __restrict__ fw,
                                              h2* __restrict__ lwh,
                                              h2* __restrict__ fwh) {
    const int i = blockIdx.x * 256 + threadIdx.x;
    if (i < LW_PAIRS) {
        const float2 v = reinterpret_cast<const float2*>(lw)[i];
        lwh[i] = __builtin_amdgcn_cvt_pkrtz(v.x, v.y);
    } else if (i < LW_PAIRS + FW_PAIRS) {
        const float2 v = reinterpret_cast<const float2*>(fw)[i - LW_PAIRS];
        fwh[i - LW_PAIRS] = __builtin_amdgcn_cvt_pkrtz(v.x, v.y);
    }
}

__global__ __launch_bounds__(1024, 4) void mlp_kernel(const float* __restrict__ pooled,
                                                      const h2* __restrict__ lwh,
                                                      const float* __restrict__ lb,
                                                      const h2* __restrict__ fwh,
                                                      const float* __restrict__ fb,
                                                      float* __restrict__ out) {
    __shared__ h2 sph[8][COMB / 2];
    __shared__ h2 sch[8][COMB / 2];

    const int tid = threadIdx.x;
    const int r0 = blockIdx.x * 8;

    const float2* __restrict__ srcp = reinterpret_cast<const float2*>(pooled + (size_t)r0 * COMB);
    for (int i = tid; i < 8 * (COMB / 2); i += 1024) {
        const float2 v = srcp[i];
        (&sph[0][0])[i] = __builtin_amdgcn_cvt_pkrtz(v.x, v.y);
    }
    __syncthreads();

    for (int idx = tid; idx < COMB * 2; idx += 1024) {
        const int c = idx >> 1, rh = (idx & 1) * 4;
        const h2* __restrict__ w = lwh + (size_t)c * 64;
        const int lb2 = (c >> 7) * 64;
        const float bias = lb[c];
        float acc[4] = {bias, bias, bias, bias};
        for (int t2 = 0; t2 < 64; t2 += 4) {
            const float4 wraw = *reinterpret_cast<const float4*>(w + t2);
            const h2 w0 = __builtin_bit_cast(h2, wraw.x);
            const h2 w1 = __builtin_bit_cast(h2, wraw.y);
            const h2 w2 = __builtin_bit_cast(h2, wraw.z);
            const h2 w3 = __builtin_bit_cast(h2, wraw.w);
#pragma unroll
            for (int r = 0; r < 4; ++r) {
                const float4 praw = *reinterpret_cast<const float4*>(&sph[rh + r][lb2 + t2]);
                acc[r] = __builtin_amdgcn_fdot2(__builtin_bit_cast(h2, praw.x), w0, acc[r], false);
                acc[r] = __builtin_amdgcn_fdot2(__builtin_bit_cast(h2, praw.y), w1, acc[r], false);
                acc[r] = __builtin_amdgcn_fdot2(__builtin_bit_cast(h2, praw.z), w2, acc[r], false);
                acc[r] = __builtin_amdgcn_fdot2(__builtin_bit_cast(h2, praw.w), w3, acc[r], false);
            }
        }
        __fp16* __restrict__ schf = reinterpret_cast<__fp16*>(&sch[0][0]);
#pragma unroll
        for (int r = 0; r < 4; ++r) schf[(rh + r) * COMB + c] = (__fp16)fmaxf(acc[r], 0.f);
    }
    __syncthreads();

    {
        const int c = tid >> 1, rh = (tid & 1) * 4;
        const h2* __restrict__ w = fwh + (size_t)c * (COMB / 2);
        const float bias = fb[c];
        float acc[4] = {bias, bias, bias, bias};
        for (int t2 = 0; t2 < COMB / 2; t2 += 4) {
            const float4 wraw = *reinterpret_cast<const float4*>(w + t2);
            const h2 w0 = __builtin_bit_cast(h2, wraw.x);
            const h2 w1 = __builtin_bit_cast(h2, wraw.y);
            const h2 w2 = __builtin_bit_cast(h2, wraw.z);
            const h2 w3 = __builtin_bit_cast(h2, wraw.w);
#pragma unroll
            for (int r = 0; r < 4; ++r) {
                const float4 craw = *reinterpret_cast<const float4*>(&sch[rh + r][t2]);
                acc[r] = __builtin_amdgcn_fdot2(__builtin_bit_cast(h2, craw.x), w0, acc[r], false);
                acc[r] = __builtin_amdgcn_fdot2(__builtin_bit_cast(h2, craw.y), w1, acc[r], false);
                acc[r] = __builtin_amdgcn_fdot2(__builtin_bit_cast(h2, craw.z), w2, acc[r], false);
                acc[r] = __builtin_amdgcn_fdot2(__builtin_bit_cast(h2, craw.w), w3, acc[r], false);
            }
        }
#pragma unroll
        for (int r = 0; r < 4; ++r) {
            out[(size_t)(r0 + rh + r) * OUTD + c] = fmaxf(acc[r], 0.f);
        }
    }
}

// Fallback mlp: in-kernel weight cvt — used if d_ws too small for packed weights
__global__ __launch_bounds__(512) void mlp_kernel_fb(const float* __restrict__ pooled,
                                                     const float* __restrict__ lw,
                                                     const float* __restrict__ lb,
                                                     const float* __restrict__ fw,
                                                     const float* __restrict__ fb,
                                                     float* __restrict__ out) {
    __shared__ h2 sph[8][COMB / 2];
    __shared__ h2 sch[8][COMB / 2];
    const int tid = threadIdx.x;
    const int r0 = blockIdx.x * 8;
    const float2* __restrict__ srcp = reinterpret_cast<const float2*>(pooled + (size_t)r0 * COMB);
    for (int i = tid; i < 8 * (COMB / 2); i += 512) {
        const float2 v = srcp[i];
        (&sph[0][0])[i] = __builtin_amdgcn_cvt_pkrtz(v.x, v.y);
    }
    __syncthreads();
    for (int c = tid; c < COMB; c += 512) {
        const float* __restrict__ w = lw + (size_t)c * POOLP;
        const int lb2 = (c >> 7) * (POOLP / 2);
        const float bias = lb[c];
        float acc[8];
#pragma unroll
        for (int r = 0; r < 8; ++r) acc[r] = bias;
        for (int t2 = 0; t2 < POOLP / 2; t2 += 4) {
            const float4 wa = *reinterpret_cast<const float4*>(w + t2 * 2);
            const float4 wb = *reinterpret_cast<const float4*>(w + t2 * 2 + 4);
            const h2 w0 = __builtin_amdgcn_cvt_pkrtz(wa.x, wa.y);
            const h2 w1 = __builtin_amdgcn_cvt_pkrtz(wa.z, wa.w);
            const h2 w2 = __builtin_amdgcn_cvt_pkrtz(wb.x, wb.y);
            const h2 w3 = __builtin_amdgcn_cvt_pkrtz(wb.z, wb.w);
#pragma unroll
            for (int r = 0; r < 8; ++r) {
                const float4 raw = *reinterpret_cast<const float4*>(&sph[r][lb2 + t2]);
                acc[r] = __builtin_amdgcn_fdot2(__builtin_bit_cast(h2, raw.x), w0, acc[r], false);
                acc[r] = __builtin_amdgcn_fdot2(__builtin_bit_cast(h2, raw.y), w1, acc[r], false);
                acc[r] = __builtin_amdgcn_fdot2(__builtin_bit_cast(h2, raw.z), w2, acc[r], false);
                acc[r] = __builtin_amdgcn_fdot2(__builtin_bit_cast(h2, raw.w), w3, acc[r], false);
            }
        }
        __fp16* __restrict__ schf = reinterpret_cast<__fp16*>(&sch[0][0]);
#pragma unroll
        for (int r = 0; r < 8; ++r) schf[r * COMB + c] = (__fp16)fmaxf(acc[r], 0.f);
    }
    __syncthreads();
    {
        const int j = tid;
        const float* __restrict__ w = fw + (size_t)j * COMB;
        const float bias = fb[j];
        float acc[8];
#pragma unroll
        for (int r = 0; r < 8; ++r) acc[r] = bias;
        for (int t2 = 0; t2 < COMB / 2; t2 += 4) {
            const float4 wa = *reinterpret_cast<const float4*>(w + t2 * 2);
            const float4 wb = *reinterpret_cast<const float4*>(w + t2 * 2 + 4);
            const h2 w0 = __builtin_amdgcn_cvt_pkrtz(wa.x, wa.y);
            const h2 w1 = __builtin_amdgcn_cvt_pkrtz(wa.z, wa.w);
            const h2 w2 = __builtin_amdgcn_cvt_pkrtz(wb.x, wb.y);
            const h2 w3 = __builtin_amdgcn_cvt_pkrtz(wb.z, wb.w);
#pragma unroll
            for (int r = 0; r < 8; ++r) {
                const float4 raw = *reinterpret_cast<const float4*>(&sch[r][t2]);
                acc[r] = __builtin_amdgcn_fdot2(__builtin_bit_cast(h2, raw.x), w0, acc[r], false);
                acc[r] = __builtin_amdgcn_fdot2(__builtin_bit_cast(h2, raw.y), w1, acc[r], false);
                acc[r] = __builtin_amdgcn_fdot2(__builtin_bit_cast(h2, raw.z), w2, acc[r], false);
                acc[r] = __builtin_amdgcn_fdot2(__builtin_bit_cast(h2, raw.w), w3, acc[r], false);
            }
        }
#pragma unroll
        for (int r = 0; r < 8; ++r) {
            out[(size_t)(r0 + r) * OUTD + j] = fmaxf(acc[r], 0.f);
        }
    }
}

extern "C" void kernel_launch(void* const* d_in, const int* in_sizes, int n_in,
                              void* d_out, int out_size, void* d_ws, size_t ws_size,
                              hipStream_t stream) {
    const float* x  = (const float*)d_in[0];
    const float* lw = (const float*)d_in[1];
    const float* lb = (const float*)d_in[2];
    const float* fw = (const float*)d_in[3];
    const float* fb = (const float*)d_in[4];
    float* out = (float*)d_out;

    float* pooled = (float*)d_ws;
    const size_t POOLED_B = (size_t)BATCH * COMB * 4;
    const size_t NEEDED   = POOLED_B + (size_t)(LW_PAIRS + FW_PAIRS) * 4;

    dwt_pool_kernel<<<BATCH * NB, NTHR, 0, stream>>>(x, pooled);

    if (ws_size >= NEEDED) {
        h2* lwh = (h2*)((char*)d_ws + POOLED_B);
        h2* fwh = (h2*)((char*)d_ws + POOLED_B + (size_t)LW_PAIRS * 4);
        pack_w<<<(LW_PAIRS + FW_PAIRS + 255) / 256, 256, 0, stream>>>(lw, fw, lwh, fwh);
        mlp_kernel<<<BATCH / 8, 1024, 0, stream>>>(pooled, lwh, lb, fwh, fb, out);
    } else {
        mlp_kernel_fb<<<BATCH / 8, 512, 0, stream>>>(pooled, lw, lb, fw, fb, out);
    }
}

// Round 9
// 93.807 us; speedup vs baseline: 1.4322x; 1.2892x over previous
//
#include <hip/hip_runtime.h>

// WaveletFeatureExtractor: db4 wavedec (5 levels, symmetric pad) -> adaptive pool 128
// -> per-level 128x128 MLP (ReLU) -> fused 640->512 MLP (ReLU).
//
// Round 9: half-row blocks. Theory: allocator chases occupancy when LDS is
// small (rounds 7/8: 12KB -> VGPR 28 -> LDS re-reads, busy-cycles 2-3x round 6);
// with LDS ~37KB occupancy is capped at 4 blocks/CU (32 waves = HW max) so the
// allocator relaxes to ~52-64 VGPR (rounds 3/6 regime) while we still get 2x
// round 6's resident blocks for barrier-stall overlap.
//  - 2 blocks/row, owned buckets [64b,64b+64), backward-derived chunk ranges
//    (runtime block-uniform scalars), halo +0.2%.
//  - mlp: round-8 (f16 pre-packed weights, 1024 thr, dot2).

#define BATCH   2048
#define SIGLEN  16384
#define N1      8195
#define N2      4101
#define N3      2054
#define N4      1030
#define N5      518
#define POOLP   128
#define COMB    640
#define OUTD    512
#define NTHR    512

#define SWZ(i) ((i) ^ ((((i) >> 5) & 7) << 2))

__device__ constexpr float LO[8] = {
     0.2303778133088965f,   0.7148465705529157f,   0.6308807679298589f,
    -0.027983769416859854f, -0.18703481171909309f,  0.030841381835560764f,
     0.0328830116668852f,  -0.010597401785069032f };
__device__ constexpr float HI[8] = {
    -0.010597401785069032f, -0.0328830116668852f,   0.030841381835560764f,
     0.18703481171909309f,  -0.027983769416859854f, -0.6308807679298589f,
     0.7148465705529157f,  -0.2303778133088965f };

__device__ __forceinline__ int symfold(int idx, int n) {
    idx = (idx < 0) ? (-1 - idx) : idx;
    idx = (idx >= n) ? (2 * n - 1 - idx) : idx;
    return idx;
}

// One DWT level over a chunk. src holds abs indices [ss,se) at slot SWZ(j-bsrc);
// outputs abs [s,e) -> dstA/dstD at slot SWZ(j-bdst). Nsrc = band length (fold).
__device__ __forceinline__ void dwt_level(const float* __restrict__ src,
                                          int ss, int se, int bsrc, int Nsrc,
                                          float* __restrict__ dstA,
                                          float* __restrict__ dstD,
                                          int s, int e, int bdst, int tid) {
    for (int j0 = (s & ~3) + tid * 4; j0 < e; j0 += NTHR * 4) {
        const int rb = 2 * j0 - 8;
        if ((rb >= ss) && (2 * j0 + 7 <= se - 1) && (j0 + 4 <= e)) {
            const int lrb = rb - bsrc;
            const float4 v0 = *reinterpret_cast<const float4*>(src + SWZ(lrb));
            const float4 v1 = *reinterpret_cast<const float4*>(src + SWZ(lrb + 4));
            const float4 v2 = *reinterpret_cast<const float4*>(src + SWZ(lrb + 8));
            const float4 v3 = *reinterpret_cast<const float4*>(src + SWZ(lrb + 12));
            float w[16];
            w[0]=v0.x;  w[1]=v0.y;  w[2]=v0.z;  w[3]=v0.w;
            w[4]=v1.x;  w[5]=v1.y;  w[6]=v1.z;  w[7]=v1.w;
            w[8]=v2.x;  w[9]=v2.y;  w[10]=v2.z; w[11]=v2.w;
            w[12]=v3.x; w[13]=v3.y; w[14]=v3.z; w[15]=v3.w;
            float a[4], d[4];
#pragma unroll
            for (int k = 0; k < 4; ++k) {
                float aa = 0.f, dd = 0.f;
#pragma unroll
                for (int t = 0; t < 8; ++t) {
                    const float v = w[2 + 2 * k + t];
                    aa = fmaf(v, LO[t], aa);
                    dd = fmaf(v, HI[t], dd);
                }
                a[k] = aa; d[k] = dd;
            }
            const int ds = j0 - bdst;
            *reinterpret_cast<float4*>(dstA + SWZ(ds)) = make_float4(a[0], a[1], a[2], a[3]);
            *reinterpret_cast<float4*>(dstD + SWZ(ds)) = make_float4(d[0], d[1], d[2], d[3]);
        } else {
            for (int k = 0; k < 4; ++k) {
                const int j = j0 + k;
                if (j < s || j >= e) continue;
                float aa = 0.f, dd = 0.f;
#pragma unroll
                for (int t = 0; t < 8; ++t) {
                    const int idx = symfold(2 * j - 6 + t, Nsrc);
                    const float v = src[SWZ(idx - bsrc)];
                    aa = fmaf(v, LO[t], aa);
                    dd = fmaf(v, HI[t], dd);
                }
                dstA[SWZ(j - bdst)] = aa;
                dstD[SWZ(j - bdst)] = dd;
            }
        }
    }
}

// Level 1 from global x (low-pass only; cD1 is dead in the reference forward).
__device__ __forceinline__ void dwt_l1(const float* __restrict__ xr,
                                       float* __restrict__ dstA,
                                       int s, int e, int bdst, int tid) {
    for (int j0 = (s & ~3) + tid * 4; j0 < e; j0 += NTHR * 4) {
        const int rb = 2 * j0 - 8;
        if ((rb >= 0) && (2 * j0 + 7 <= SIGLEN - 1) && (j0 + 4 <= e)) {
            const float4* s4 = reinterpret_cast<const float4*>(xr + rb);
            const float4 v0 = s4[0], v1 = s4[1], v2 = s4[2], v3 = s4[3];
            float w[16];
            w[0]=v0.x;  w[1]=v0.y;  w[2]=v0.z;  w[3]=v0.w;
            w[4]=v1.x;  w[5]=v1.y;  w[6]=v1.z;  w[7]=v1.w;
            w[8]=v2.x;  w[9]=v2.y;  w[10]=v2.z; w[11]=v2.w;
            w[12]=v3.x; w[13]=v3.y; w[14]=v3.z; w[15]=v3.w;
            float a[4];
#pragma unroll
            for (int k = 0; k < 4; ++k) {
                float aa = 0.f;
#pragma unroll
                for (int t = 0; t < 8; ++t) aa = fmaf(w[2 + 2 * k + t], LO[t], aa);
                a[k] = aa;
            }
            *reinterpret_cast<float4*>(dstA + SWZ(j0 - bdst)) = make_float4(a[0], a[1], a[2], a[3]);
        } else {
            for (int k = 0; k < 4; ++k) {
                const int j = j0 + k;
                if (j < s || j >= e) continue;
                float aa = 0.f;
#pragma unroll
                for (int t = 0; t < 8; ++t) {
                    const int idx = symfold(2 * j - 6 + t, SIGLEN);
                    aa = fmaf(xr[idx], LO[t], aa);
                }
                dstA[SWZ(j - bdst)] = aa;
            }
        }
    }
}

// Pool the block's 64 owned buckets of one band; 8 threads/bucket.
__device__ __forceinline__ void pool64(const float* __restrict__ buf, int base, int N,
                                       int p0, float* __restrict__ dst, int tid) {
    const int p = p0 + (tid >> 3), sub = tid & 7;
    const int s = (p * N) >> 7;
    const int e = ((p + 1) * N + 127) >> 7;
    float acc = 0.f;
    for (int t = s + sub; t < e; t += 8) acc += buf[SWZ(t - base)];
    acc += __shfl_xor(acc, 1);
    acc += __shfl_xor(acc, 2);
    acc += __shfl_xor(acc, 4);
    if (sub == 0) dst[p] = acc / (float)(e - s);
}

__global__ __launch_bounds__(NTHR, 4) void dwt_pool_kernel(const float* __restrict__ x,
                                                           float* __restrict__ pooled) {
    __shared__ __align__(16) float A[4160];    // cA1 / cA3 / cA5 chunks
    __shared__ __align__(16) float Bb[2112];   // cA2 / cA4 chunks
    __shared__ __align__(16) float D1[2112];   // cD2 / cD4 chunks
    __shared__ __align__(16) float D2[1056];   // cD3 / cD5 chunks

    const int tid = threadIdx.x;
    const int row = blockIdx.x >> 1;
    const int b   = blockIdx.x & 1;
    const int p0  = b << 6;                    // owned buckets [p0, p0+64)

    const float* __restrict__ xr = x + (size_t)row * SIGLEN;
    float* __restrict__ pr = pooled + (size_t)row * COMB;

    // Owned-bucket element ranges (torch: [p*N>>7, ((p+1)*N+127)>>7))
    const int sP5 = (p0 * N5) >> 7, eP5 = ((p0 + 64) * N5 + 127) >> 7;
    const int sP4 = (p0 * N4) >> 7, eP4 = ((p0 + 64) * N4 + 127) >> 7;
    const int sP3 = (p0 * N3) >> 7, eP3 = ((p0 + 64) * N3 + 127) >> 7;
    const int sP2 = (p0 * N2) >> 7, eP2 = ((p0 + 64) * N2 + 127) >> 7;

    // Chunk ranges, backward: pool range U expand(child need)
    const int s5 = sP5, e5 = eP5;
    int s4 = min(sP4, 2 * s5 - 6); s4 = max(s4, 0);
    int e4 = max(eP4, 2 * e5);     e4 = min(e4, N4);
    int s3 = min(sP3, 2 * s4 - 6); s3 = max(s3, 0);
    int e3 = max(eP3, 2 * e4);     e3 = min(e3, N3);
    int s2 = min(sP2, 2 * s3 - 6); s2 = max(s2, 0);
    int e2 = max(eP2, 2 * e3);     e2 = min(e2, N2);
    int s1 = max(2 * s2 - 6, 0);
    int e1 = min(2 * e2, N1);

    const int b1 = (s1 & ~3) - 8, b2 = (s2 & ~3) - 8, b3 = (s3 & ~3) - 8;
    const int b4 = (s4 & ~3) - 8, b5 = (s5 & ~3) - 8;

    // P0: level 1 global -> A
    dwt_l1(xr, A, s1, e1, b1, tid);
    __syncthreads();
    // P1: level 2: A -> Bb(cA2), D1(cD2)
    dwt_level(A, s1, e1, b1, N1, Bb, D1, s2, e2, b2, tid);
    __syncthreads();
    // P2: level 3: Bb -> A(cA3), D2(cD3)   || pool cD2 -> slot 4
    dwt_level(Bb, s2, e2, b2, N2, A, D2, s3, e3, b3, tid);
    pool64(D1, b2, N2, p0, pr + 4 * POOLP, tid);
    __syncthreads();
    // P3: level 4: A -> Bb(cA4), D1(cD4)   || pool cD3 -> slot 3
    dwt_level(A, s3, e3, b3, N3, Bb, D1, s4, e4, b4, tid);
    pool64(D2, b3, N3, p0, pr + 3 * POOLP, tid);
    __syncthreads();
    // P4: level 5: Bb -> A(cA5), D2(cD5)   || pool cD4 -> slot 2
    dwt_level(Bb, s4, e4, b4, N4, A, D2, s5, e5, b5, tid);
    pool64(D1, b4, N4, p0, pr + 2 * POOLP, tid);
    __syncthreads();
    // P5: pool cA5 -> slot 0, cD5 -> slot 1
    pool64(A,  b5, N5, p0, pr + 0 * POOLP, tid);
    pool64(D2, b5, N5, p0, pr + 1 * POOLP, tid);
}

// ---------------- MLP (unchanged from round 8) ----------------

typedef __fp16 h2 __attribute__((ext_vector_type(2)));

#define LW_PAIRS (5 * 128 * 128 / 2)
#define FW_PAIRS (512 * 640 / 2)

__global__ __launch_bounds__(256) void pack_w(const float* __restrict__ lw,
                                              const float* __restrict__ fw,
                                              h2* __restrict__ lwh,
                                              h2* __restrict__ fwh) {
    const int i = blockIdx.x * 256 + threadIdx.x;
    if (i < LW_PAIRS) {
        const float2 v = reinterpret_cast<const float2*>(lw)[i];
        lwh[i] = __builtin_amdgcn_cvt_pkrtz(v.x, v.y);
    } else if (i < LW_PAIRS + FW_PAIRS) {
        const float2 v = reinterpret_cast<const float2*>(fw)[i - LW_PAIRS];
        fwh[i - LW_PAIRS] = __builtin_amdgcn_cvt_pkrtz(v.x, v.y);
    }
}

__global__ __launch_bounds__(1024, 4) void mlp_kernel(const float* __restrict__ pooled,
                                                      const h2* __restrict__ lwh,
                                                      const float* __restrict__ lb,
                                                      const h2* __restrict__ fwh,
                                                      const float* __restrict__ fb,
                                                      float* __restrict__ out) {
    __shared__ h2 sph[8][COMB / 2];
    __shared__ h2 sch[8][COMB / 2];

    const int tid = threadIdx.x;
    const int r0 = blockIdx.x * 8;

    const float2* __restrict__ srcp = reinterpret_cast<const float2*>(pooled + (size_t)r0 * COMB);
    for (int i = tid; i < 8 * (COMB / 2); i += 1024) {
        const float2 v = srcp[i];
        (&sph[0][0])[i] = __builtin_amdgcn_cvt_pkrtz(v.x, v.y);
    }
    __syncthreads();

    for (int idx = tid; idx < COMB * 2; idx += 1024) {
        const int c = idx >> 1, rh = (idx & 1) * 4;
        const h2* __restrict__ w = lwh + (size_t)c * 64;
        const int lb2 = (c >> 7) * 64;
        const float bias = lb[c];
        float acc[4] = {bias, bias, bias, bias};
        for (int t2 = 0; t2 < 64; t2 += 4) {
            const float4 wraw = *reinterpret_cast<const float4*>(w + t2);
            const h2 w0 = __builtin_bit_cast(h2, wraw.x);
            const h2 w1 = __builtin_bit_cast(h2, wraw.y);
            const h2 w2 = __builtin_bit_cast(h2, wraw.z);
            const h2 w3 = __builtin_bit_cast(h2, wraw.w);
#pragma unroll
            for (int r = 0; r < 4; ++r) {
                const float4 praw = *reinterpret_cast<const float4*>(&sph[rh + r][lb2 + t2]);
                acc[r] = __builtin_amdgcn_fdot2(__builtin_bit_cast(h2, praw.x), w0, acc[r], false);
                acc[r] = __builtin_amdgcn_fdot2(__builtin_bit_cast(h2, praw.y), w1, acc[r], false);
                acc[r] = __builtin_amdgcn_fdot2(__builtin_bit_cast(h2, praw.z), w2, acc[r], false);
                acc[r] = __builtin_amdgcn_fdot2(__builtin_bit_cast(h2, praw.w), w3, acc[r], false);
            }
        }
        __fp16* __restrict__ schf = reinterpret_cast<__fp16*>(&sch[0][0]);
#pragma unroll
        for (int r = 0; r < 4; ++r) schf[(rh + r) * COMB + c] = (__fp16)fmaxf(acc[r], 0.f);
    }
    __syncthreads();

    {
        const int c = tid >> 1, rh = (tid & 1) * 4;
        const h2* __restrict__ w = fwh + (size_t)c * (COMB / 2);
        const float bias = fb[c];
        float acc[4] = {bias, bias, bias, bias};
        for (int t2 = 0; t2 < COMB / 2; t2 += 4) {
            const float4 wraw = *reinterpret_cast<const float4*>(w + t2);
            const h2 w0 = __builtin_bit_cast(h2, wraw.x);
            const h2 w1 = __builtin_bit_cast(h2, wraw.y);
            const h2 w2 = __builtin_bit_cast(h2, wraw.z);
            const h2 w3 = __builtin_bit_cast(h2, wraw.w);
#pragma unroll
            for (int r = 0; r < 4; ++r) {
                const float4 craw = *reinterpret_cast<const float4*>(&sch[rh + r][t2]);
                acc[r] = __builtin_amdgcn_fdot2(__builtin_bit_cast(h2, craw.x), w0, acc[r], false);
                acc[r] = __builtin_amdgcn_fdot2(__builtin_bit_cast(h2, craw.y), w1, acc[r], false);
                acc[r] = __builtin_amdgcn_fdot2(__builtin_bit_cast(h2, craw.z), w2, acc[r], false);
                acc[r] = __builtin_amdgcn_fdot2(__builtin_bit_cast(h2, craw.w), w3, acc[r], false);
            }
        }
#pragma unroll
        for (int r = 0; r < 4; ++r) {
            out[(size_t)(r0 + rh + r) * OUTD + c] = fmaxf(acc[r], 0.f);
        }
    }
}

// Fallback mlp: in-kernel weight cvt — used if d_ws too small for packed weights
__global__ __launch_bounds__(512) void mlp_kernel_fb(const float* __restrict__ pooled,
                                                     const float* __restrict__ lw,
                                                     const float* __restrict__ lb,
                                                     const float* __restrict__ fw,
                                                     const float* __restrict__ fb,
                                                     float* __restrict__ out) {
    __shared__ h2 sph[8][COMB / 2];
    __shared__ h2 sch[8][COMB / 2];
    const int tid = threadIdx.x;
    const int r0 = blockIdx.x * 8;
    const float2* __restrict__ srcp = reinterpret_cast<const float2*>(pooled + (size_t)r0 * COMB);
    for (int i = tid; i < 8 * (COMB / 2); i += 512) {
        const float2 v = srcp[i];
        (&sph[0][0])[i] = __builtin_amdgcn_cvt_pkrtz(v.x, v.y);
    }
    __syncthreads();
    for (int c = tid; c < COMB; c += 512) {
        const float* __restrict__ w = lw + (size_t)c * POOLP;
        const int lb2 = (c >> 7) * (POOLP / 2);
        const float bias = lb[c];
        float acc[8];
#pragma unroll
        for (int r = 0; r < 8; ++r) acc[r] = bias;
        for (int t2 = 0; t2 < POOLP / 2; t2 += 4) {
            const float4 wa = *reinterpret_cast<const float4*>(w + t2 * 2);
            const float4 wb = *reinterpret_cast<const float4*>(w + t2 * 2 + 4);
            const h2 w0 = __builtin_amdgcn_cvt_pkrtz(wa.x, wa.y);
            const h2 w1 = __builtin_amdgcn_cvt_pkrtz(wa.z, wa.w);
            const h2 w2 = __builtin_amdgcn_cvt_pkrtz(wb.x, wb.y);
            const h2 w3 = __builtin_amdgcn_cvt_pkrtz(wb.z, wb.w);
#pragma unroll
            for (int r = 0; r < 8; ++r) {
                const float4 raw = *reinterpret_cast<const float4*>(&sph[r][lb2 + t2]);
                acc[r] = __builtin_amdgcn_fdot2(__builtin_bit_cast(h2, raw.x), w0, acc[r], false);
                acc[r] = __builtin_amdgcn_fdot2(__builtin_bit_cast(h2, raw.y), w1, acc[r], false);
                acc[r] = __builtin_amdgcn_fdot2(__builtin_bit_cast(h2, raw.z), w2, acc[r], false);
                acc[r] = __builtin_amdgcn_fdot2(__builtin_bit_cast(h2, raw.w), w3, acc[r], false);
            }
        }
        __fp16* __restrict__ schf = reinterpret_cast<__fp16*>(&sch[0][0]);
#pragma unroll
        for (int r = 0; r < 8; ++r) schf[r * COMB + c] = (__fp16)fmaxf(acc[r], 0.f);
    }
    __syncthreads();
    {
        const int j = tid;
        const float* __restrict__ w = fw + (size_t)j * COMB;
        const float bias = fb[j];
        float acc[8];
#pragma unroll
        for (int r = 0; r < 8; ++r) acc[r] = bias;
        for (int t2 = 0; t2 < COMB / 2; t2 += 4) {
            const float4 wa = *reinterpret_cast<const float4*>(w + t2 * 2);
            const float4 wb = *reinterpret_cast<const float4*>(w + t2 * 2 + 4);
            const h2 w0 = __builtin_amdgcn_cvt_pkrtz(wa.x, wa.y);
            const h2 w1 = __builtin_amdgcn_cvt_pkrtz(wa.z, wa.w);
            const h2 w2 = __builtin_amdgcn_cvt_pkrtz(wb.x, wb.y);
            const h2 w3 = __builtin_amdgcn_cvt_pkrtz(wb.z, wb.w);
#pragma unroll
            for (int r = 0; r < 8; ++r) {
                const float4 raw = *reinterpret_cast<const float4*>(&sch[r][t2]);
                acc[r] = __builtin_amdgcn_fdot2(__builtin_bit_cast(h2, raw.x), w0, acc[r], false);
                acc[r] = __builtin_amdgcn_fdot2(__builtin_bit_cast(h2, raw.y), w1, acc[r], false);
                acc[r] = __builtin_amdgcn_fdot2(__builtin_bit_cast(h2, raw.z), w2, acc[r], false);
                acc[r] = __builtin_amdgcn_fdot2(__builtin_bit_cast(h2, raw.w), w3, acc[r], false);
            }
        }
#pragma unroll
        for (int r = 0; r < 8; ++r) {
            out[(size_t)(r0 + r) * OUTD + j] = fmaxf(acc[r], 0.f);
        }
    }
}

extern "C" void kernel_launch(void* const* d_in, const int* in_sizes, int n_in,
                              void* d_out, int out_size, void* d_ws, size_t ws_size,
                              hipStream_t stream) {
    const float* x  = (const float*)d_in[0];
    const float* lw = (const float*)d_in[1];
    const float* lb = (const float*)d_in[2];
    const float* fw = (const float*)d_in[3];
    const float* fb = (const float*)d_in[4];
    float* out = (float*)d_out;

    float* pooled = (float*)d_ws;
    const size_t POOLED_B = (size_t)BATCH * COMB * 4;
    const size_t NEEDED   = POOLED_B + (size_t)(LW_PAIRS + FW_PAIRS) * 4;

    dwt_pool_kernel<<<BATCH * 2, NTHR, 0, stream>>>(x, pooled);

    if (ws_size >= NEEDED) {
        h2* lwh = (h2*)((char*)d_ws + POOLED_B);
        h2* fwh = (h2*)((char*)d_ws + POOLED_B + (size_t)LW_PAIRS * 4);
        pack_w<<<(LW_PAIRS + FW_PAIRS + 255) / 256, 256, 0, stream>>>(lw, fw, lwh, fwh);
        mlp_kernel<<<BATCH / 8, 1024, 0, stream>>>(pooled, lwh, lb, fwh, fb, out);
    } else {
        mlp_kernel_fb<<<BATCH / 8, 512, 0, stream>>>(pooled, lw, lb, fw, fb, out);
    }
}

// Round 10
// 89.970 us; speedup vs baseline: 1.4933x; 1.0427x over previous
//
#include <hip/hip_runtime.h>

// WaveletFeatureExtractor: db4 wavedec (5 levels, symmetric pad) -> adaptive pool 128
// -> per-level 128x128 MLP (ReLU) -> fused 640->512 MLP (ReLU).
//
// Round 10 = round 9 (2 blocks/row, 37KB LDS -> 4 blocks/CU, 78% occ) + round 8's
// constexpr geometry (template<B> body; bounds checks fold, SWZ folds, loop
// splits into pure fast path + boundary epilogue). r9 busy-equiv was 44 us vs
// r6's 28 with constexpr geometry -> templating targets that ~16 us.
// LDS buffers padded +32 (r9's SWZ halo writes could exceed the arrays; was
// benign only by phase ordering).

#define BATCH   2048
#define SIGLEN  16384
#define N1      8195
#define N2      4101
#define N3      2054
#define N4      1030
#define N5      518
#define POOLP   128
#define COMB    640
#define OUTD    512
#define NTHR    512

#define SWZ(i) ((i) ^ ((((i) >> 5) & 7) << 2))

__device__ constexpr float LO[8] = {
     0.2303778133088965f,   0.7148465705529157f,   0.6308807679298589f,
    -0.027983769416859854f, -0.18703481171909309f,  0.030841381835560764f,
     0.0328830116668852f,  -0.010597401785069032f };
__device__ constexpr float HI[8] = {
    -0.010597401785069032f, -0.0328830116668852f,   0.030841381835560764f,
     0.18703481171909309f,  -0.027983769416859854f, -0.6308807679298589f,
     0.7148465705529157f,  -0.2303778133088965f };

__device__ __forceinline__ int symfold(int idx, int n) {
    idx = (idx < 0) ? (-1 - idx) : idx;
    idx = (idx >= n) ? (2 * n - 1 - idx) : idx;
    return idx;
}

constexpr int cmin(int a, int b) { return a < b ? a : b; }
constexpr int cmax(int a, int b) { return a > b ? a : b; }

// One DWT level over a chunk; geometry compile-time. src holds abs [SS,SE) at
// slot SWZ(j-BSRC); outputs abs [S,E) -> dstA/dstD at slot SWZ(j-BDST).
template<int SS, int SE, int BSRC, int NSRC, int S, int E, int BDST>
__device__ __forceinline__ void dwt_chunk(const float* __restrict__ src,
                                          float* __restrict__ dstA,
                                          float* __restrict__ dstD,
                                          int tid) {
    for (int j0 = (S & ~3) + tid * 4; j0 < E; j0 += NTHR * 4) {
        const int rb = 2 * j0 - 8;
        if ((rb >= SS) && (2 * j0 + 7 <= SE - 1) && (j0 + 4 <= E)) {
            const int lrb = rb - BSRC;
            const float4 v0 = *reinterpret_cast<const float4*>(src + SWZ(lrb));
            const float4 v1 = *reinterpret_cast<const float4*>(src + SWZ(lrb + 4));
            const float4 v2 = *reinterpret_cast<const float4*>(src + SWZ(lrb + 8));
            const float4 v3 = *reinterpret_cast<const float4*>(src + SWZ(lrb + 12));
            float w[16];
            w[0]=v0.x;  w[1]=v0.y;  w[2]=v0.z;  w[3]=v0.w;
            w[4]=v1.x;  w[5]=v1.y;  w[6]=v1.z;  w[7]=v1.w;
            w[8]=v2.x;  w[9]=v2.y;  w[10]=v2.z; w[11]=v2.w;
            w[12]=v3.x; w[13]=v3.y; w[14]=v3.z; w[15]=v3.w;
            float a[4], d[4];
#pragma unroll
            for (int k = 0; k < 4; ++k) {
                float aa = 0.f, dd = 0.f;
#pragma unroll
                for (int t = 0; t < 8; ++t) {
                    const float v = w[2 + 2 * k + t];
                    aa = fmaf(v, LO[t], aa);
                    dd = fmaf(v, HI[t], dd);
                }
                a[k] = aa; d[k] = dd;
            }
            const int ds = j0 - BDST;
            *reinterpret_cast<float4*>(dstA + SWZ(ds)) = make_float4(a[0], a[1], a[2], a[3]);
            *reinterpret_cast<float4*>(dstD + SWZ(ds)) = make_float4(d[0], d[1], d[2], d[3]);
        } else {
            for (int k = 0; k < 4; ++k) {
                const int j = j0 + k;
                if (j < S || j >= E) continue;
                float aa = 0.f, dd = 0.f;
#pragma unroll
                for (int t = 0; t < 8; ++t) {
                    const int idx = symfold(2 * j - 6 + t, NSRC);
                    const float v = src[SWZ(idx - BSRC)];
                    aa = fmaf(v, LO[t], aa);
                    dd = fmaf(v, HI[t], dd);
                }
                dstA[SWZ(j - BDST)] = aa;
                dstD[SWZ(j - BDST)] = dd;
            }
        }
    }
}

// Level 1 from global x (low-pass only; cD1 is dead in the reference forward).
template<int S, int E, int BDST>
__device__ __forceinline__ void dwt_l1(const float* __restrict__ xr,
                                       float* __restrict__ dstA, int tid) {
    for (int j0 = (S & ~3) + tid * 4; j0 < E; j0 += NTHR * 4) {
        const int rb = 2 * j0 - 8;
        if ((rb >= 0) && (2 * j0 + 7 <= SIGLEN - 1) && (j0 + 4 <= E)) {
            const float4* s4 = reinterpret_cast<const float4*>(xr + rb);
            const float4 v0 = s4[0], v1 = s4[1], v2 = s4[2], v3 = s4[3];
            float w[16];
            w[0]=v0.x;  w[1]=v0.y;  w[2]=v0.z;  w[3]=v0.w;
            w[4]=v1.x;  w[5]=v1.y;  w[6]=v1.z;  w[7]=v1.w;
            w[8]=v2.x;  w[9]=v2.y;  w[10]=v2.z; w[11]=v2.w;
            w[12]=v3.x; w[13]=v3.y; w[14]=v3.z; w[15]=v3.w;
            float a[4];
#pragma unroll
            for (int k = 0; k < 4; ++k) {
                float aa = 0.f;
#pragma unroll
                for (int t = 0; t < 8; ++t) aa = fmaf(w[2 + 2 * k + t], LO[t], aa);
                a[k] = aa;
            }
            *reinterpret_cast<float4*>(dstA + SWZ(j0 - BDST)) = make_float4(a[0], a[1], a[2], a[3]);
        } else {
            for (int k = 0; k < 4; ++k) {
                const int j = j0 + k;
                if (j < S || j >= E) continue;
                float aa = 0.f;
#pragma unroll
                for (int t = 0; t < 8; ++t) {
                    const int idx = symfold(2 * j - 6 + t, SIGLEN);
                    aa = fmaf(xr[idx], LO[t], aa);
                }
                dstA[SWZ(j - BDST)] = aa;
            }
        }
    }
}

// Pool the block's 64 owned buckets of one band; 8 threads/bucket.
template<int N, int BASE, int P0>
__device__ __forceinline__ void pool64(const float* __restrict__ buf,
                                       float* __restrict__ dst, int tid) {
    const int p = P0 + (tid >> 3), sub = tid & 7;
    const int s = (p * N) >> 7;
    const int e = ((p + 1) * N + 127) >> 7;
    float acc = 0.f;
    for (int t = s + sub; t < e; t += 8) acc += buf[SWZ(t - BASE)];
    acc += __shfl_xor(acc, 1);
    acc += __shfl_xor(acc, 2);
    acc += __shfl_xor(acc, 4);
    if (sub == 0) dst[p] = acc / (float)(e - s);
}

template<int B>
__device__ __forceinline__ void dwt_body(const float* __restrict__ xr,
                                         float* __restrict__ pr,
                                         float* __restrict__ A,
                                         float* __restrict__ Bb,
                                         float* __restrict__ D1,
                                         float* __restrict__ D2,
                                         int tid) {
    constexpr int p0 = B * 64;
    constexpr int sP5 = (p0 * N5) >> 7, eP5 = ((p0 + 64) * N5 + 127) >> 7;
    constexpr int sP4 = (p0 * N4) >> 7, eP4 = ((p0 + 64) * N4 + 127) >> 7;
    constexpr int sP3 = (p0 * N3) >> 7, eP3 = ((p0 + 64) * N3 + 127) >> 7;
    constexpr int sP2 = (p0 * N2) >> 7, eP2 = ((p0 + 64) * N2 + 127) >> 7;
    constexpr int s5 = sP5, e5 = cmin(eP5, N5);
    constexpr int s4 = cmax(cmin(sP4, 2 * s5 - 6), 0);
    constexpr int e4 = cmin(cmax(eP4, 2 * e5), N4);
    constexpr int s3 = cmax(cmin(sP3, 2 * s4 - 6), 0);
    constexpr int e3 = cmin(cmax(eP3, 2 * e4), N3);
    constexpr int s2 = cmax(cmin(sP2, 2 * s3 - 6), 0);
    constexpr int e2 = cmin(cmax(eP2, 2 * e3), N2);
    constexpr int s1 = cmax(2 * s2 - 6, 0);
    constexpr int e1 = cmin(2 * e2, N1);
    constexpr int b1 = (s1 & ~3) - 8, b2 = (s2 & ~3) - 8, b3 = (s3 & ~3) - 8;
    constexpr int b4 = (s4 & ~3) - 8, b5 = (s5 & ~3) - 8;

    dwt_l1<s1, e1, b1>(xr, A, tid);
    __syncthreads();
    dwt_chunk<s1, e1, b1, N1, s2, e2, b2>(A, Bb, D1, tid);
    __syncthreads();
    dwt_chunk<s2, e2, b2, N2, s3, e3, b3>(Bb, A, D2, tid);
    pool64<N2, b2, p0>(D1, pr + 4 * POOLP, tid);
    __syncthreads();
    dwt_chunk<s3, e3, b3, N3, s4, e4, b4>(A, Bb, D1, tid);
    pool64<N3, b3, p0>(D2, pr + 3 * POOLP, tid);
    __syncthreads();
    dwt_chunk<s4, e4, b4, N4, s5, e5, b5>(Bb, A, D2, tid);
    pool64<N4, b4, p0>(D1, pr + 2 * POOLP, tid);
    __syncthreads();
    pool64<N5, b5, p0>(A,  pr + 0 * POOLP, tid);
    pool64<N5, b5, p0>(D2, pr + 1 * POOLP, tid);
}

__global__ __launch_bounds__(NTHR, 4) void dwt_pool_kernel(const float* __restrict__ x,
                                                           float* __restrict__ pooled) {
    __shared__ __align__(16) float A[4192];    // cA1 / cA3 / cA5 chunks (+32 pad)
    __shared__ __align__(16) float Bb[2144];   // cA2 / cA4 chunks
    __shared__ __align__(16) float D1[2144];   // cD2 / cD4 chunks
    __shared__ __align__(16) float D2[1088];   // cD3 / cD5 chunks

    const int tid = threadIdx.x;
    const int row = blockIdx.x >> 1;
    const float* __restrict__ xr = x + (size_t)row * SIGLEN;
    float* __restrict__ pr = pooled + (size_t)row * COMB;

    if (blockIdx.x & 1) dwt_body<1>(xr, pr, A, Bb, D1, D2, tid);
    else                dwt_body<0>(xr, pr, A, Bb, D1, D2, tid);
}

// ---------------- MLP (unchanged from round 8/9) ----------------

typedef __fp16 h2 __attribute__((ext_vector_type(2)));

#define LW_PAIRS (5 * 128 * 128 / 2)
#define FW_PAIRS (512 * 640 / 2)

__global__ __launch_bounds__(256) void pack_w(const float* __restrict__ lw,
                                              const float* __restrict__ fw,
                                              h2* __restrict__ lwh,
                                              h2* __restrict__ fwh) {
    const int i = blockIdx.x * 256 + threadIdx.x;
    if (i < LW_PAIRS) {
        const float2 v = reinterpret_cast<const float2*>(lw)[i];
        lwh[i] = __builtin_amdgcn_cvt_pkrtz(v.x, v.y);
    } else if (i < LW_PAIRS + FW_PAIRS) {
        const float2 v = reinterpret_cast<const float2*>(fw)[i - LW_PAIRS];
        fwh[i - LW_PAIRS] = __builtin_amdgcn_cvt_pkrtz(v.x, v.y);
    }
}

__global__ __launch_bounds__(1024, 4) void mlp_kernel(const float* __restrict__ pooled,
                                                      const h2* __restrict__ lwh,
                                                      const float* __restrict__ lb,
                                                      const h2* __restrict__ fwh,
                                                      const float* __restrict__ fb,
                                                      float* __restrict__ out) {
    __shared__ h2 sph[8][COMB / 2];
    __shared__ h2 sch[8][COMB / 2];

    const int tid = threadIdx.x;
    const int r0 = blockIdx.x * 8;

    const float2* __restrict__ srcp = reinterpret_cast<const float2*>(pooled + (size_t)r0 * COMB);
    for (int i = tid; i < 8 * (COMB / 2); i += 1024) {
        const float2 v = srcp[i];
        (&sph[0][0])[i] = __builtin_amdgcn_cvt_pkrtz(v.x, v.y);
    }
    __syncthreads();

    for (int idx = tid; idx < COMB * 2; idx += 1024) {
        const int c = idx >> 1, rh = (idx & 1) * 4;
        const h2* __restrict__ w = lwh + (size_t)c * 64;
        const int lb2 = (c >> 7) * 64;
        const float bias = lb[c];
        float acc[4] = {bias, bias, bias, bias};
        for (int t2 = 0; t2 < 64; t2 += 4) {
            const float4 wraw = *reinterpret_cast<const float4*>(w + t2);
            const h2 w0 = __builtin_bit_cast(h2, wraw.x);
            const h2 w1 = __builtin_bit_cast(h2, wraw.y);
            const h2 w2 = __builtin_bit_cast(h2, wraw.z);
            const h2 w3 = __builtin_bit_cast(h2, wraw.w);
#pragma unroll
            for (int r = 0; r < 4; ++r) {
                const float4 praw = *reinterpret_cast<const float4*>(&sph[rh + r][lb2 + t2]);
                acc[r] = __builtin_amdgcn_fdot2(__builtin_bit_cast(h2, praw.x), w0, acc[r], false);
                acc[r] = __builtin_amdgcn_fdot2(__builtin_bit_cast(h2, praw.y), w1, acc[r], false);
                acc[r] = __builtin_amdgcn_fdot2(__builtin_bit_cast(h2, praw.z), w2, acc[r], false);
                acc[r] = __builtin_amdgcn_fdot2(__builtin_bit_cast(h2, praw.w), w3, acc[r], false);
            }
        }
        __fp16* __restrict__ schf = reinterpret_cast<__fp16*>(&sch[0][0]);
#pragma unroll
        for (int r = 0; r < 4; ++r) schf[(rh + r) * COMB + c] = (__fp16)fmaxf(acc[r], 0.f);
    }
    __syncthreads();

    {
        const int c = tid >> 1, rh = (tid & 1) * 4;
        const h2* __restrict__ w = fwh + (size_t)c * (COMB / 2);
        const float bias = fb[c];
        float acc[4] = {bias, bias, bias, bias};
        for (int t2 = 0; t2 < COMB / 2; t2 += 4) {
            const float4 wraw = *reinterpret_cast<const float4*>(w + t2);
            const h2 w0 = __builtin_bit_cast(h2, wraw.x);
            const h2 w1 = __builtin_bit_cast(h2, wraw.y);
            const h2 w2 = __builtin_bit_cast(h2, wraw.z);
            const h2 w3 = __builtin_bit_cast(h2, wraw.w);
#pragma unroll
            for (int r = 0; r < 4; ++r) {
                const float4 craw = *reinterpret_cast<const float4*>(&sch[rh + r][t2]);
                acc[r] = __builtin_amdgcn_fdot2(__builtin_bit_cast(h2, craw.x), w0, acc[r], false);
                acc[r] = __builtin_amdgcn_fdot2(__builtin_bit_cast(h2, craw.y), w1, acc[r], false);
                acc[r] = __builtin_amdgcn_fdot2(__builtin_bit_cast(h2, craw.z), w2, acc[r], false);
                acc[r] = __builtin_amdgcn_fdot2(__builtin_bit_cast(h2, craw.w), w3, acc[r], false);
            }
        }
#pragma unroll
        for (int r = 0; r < 4; ++r) {
            out[(size_t)(r0 + rh + r) * OUTD + c] = fmaxf(acc[r], 0.f);
        }
    }
}

// Fallback mlp: in-kernel weight cvt — used if d_ws too small for packed weights
__global__ __launch_bounds__(512) void mlp_kernel_fb(const float* __restrict__ pooled,
                                                     const float* __restrict__ lw,
                                                     const float* __restrict__ lb,
                                                     const float* __restrict__ fw,
                                                     const float* __restrict__ fb,
                                                     float* __restrict__ out) {
    __shared__ h2 sph[8][COMB / 2];
    __shared__ h2 sch[8][COMB / 2];
    const int tid = threadIdx.x;
    const int r0 = blockIdx.x * 8;
    const float2* __restrict__ srcp = reinterpret_cast<const float2*>(pooled + (size_t)r0 * COMB);
    for (int i = tid; i < 8 * (COMB / 2); i += 512) {
        const float2 v = srcp[i];
        (&sph[0][0])[i] = __builtin_amdgcn_cvt_pkrtz(v.x, v.y);
    }
    __syncthreads();
    for (int c = tid; c < COMB; c += 512) {
        const float* __restrict__ w = lw + (size_t)c * POOLP;
        const int lb2 = (c >> 7) * (POOLP / 2);
        const float bias = lb[c];
        float acc[8];
#pragma unroll
        for (int r = 0; r < 8; ++r) acc[r] = bias;
        for (int t2 = 0; t2 < POOLP / 2; t2 += 4) {
            const float4 wa = *reinterpret_cast<const float4*>(w + t2 * 2);
            const float4 wb = *reinterpret_cast<const float4*>(w + t2 * 2 + 4);
            const h2 w0 = __builtin_amdgcn_cvt_pkrtz(wa.x, wa.y);
            const h2 w1 = __builtin_amdgcn_cvt_pkrtz(wa.z, wa.w);
            const h2 w2 = __builtin_amdgcn_cvt_pkrtz(wb.x, wb.y);
            const h2 w3 = __builtin_amdgcn_cvt_pkrtz(wb.z, wb.w);
#pragma unroll
            for (int r = 0; r < 8; ++r) {
                const float4 raw = *reinterpret_cast<const float4*>(&sph[r][lb2 + t2]);
                acc[r] = __builtin_amdgcn_fdot2(__builtin_bit_cast(h2, raw.x), w0, acc[r], false);
                acc[r] = __builtin_amdgcn_fdot2(__builtin_bit_cast(h2, raw.y), w1, acc[r], false);
                acc[r] = __builtin_amdgcn_fdot2(__builtin_bit_cast(h2, raw.z), w2, acc[r], false);
                acc[r] = __builtin_amdgcn_fdot2(__builtin_bit_cast(h2, raw.w), w3, acc[r], false);
            }
        }
        __fp16* __restrict__ schf = reinterpret_cast<__fp16*>(&sch[0][0]);
#pragma unroll
        for (int r = 0; r < 8; ++r) schf[r * COMB + c] = (__fp16)fmaxf(acc[r], 0.f);
    }
    __syncthreads();
    {
        const int j = tid;
        const float* __restrict__ w = fw + (size_t)j * COMB;
        const float bias = fb[j];
        float acc[8];
#pragma unroll
        for (int r = 0; r < 8; ++r) acc[r] = bias;
        for (int t2 = 0; t2 < COMB / 2; t2 += 4) {
            const float4 wa = *reinterpret_cast<const float4*>(w + t2 * 2);
            const float4 wb = *reinterpret_cast<const float4*>(w + t2 * 2 + 4);
            const h2 w0 = __builtin_amdgcn_cvt_pkrtz(wa.x, wa.y);
            const h2 w1 = __builtin_amdgcn_cvt_pkrtz(wa.z, wa.w);
            const h2 w2 = __builtin_amdgcn_cvt_pkrtz(wb.x, wb.y);
            const h2 w3 = __builtin_amdgcn_cvt_pkrtz(wb.z, wb.w);
#pragma unroll
            for (int r = 0; r < 8; ++r) {
                const float4 raw = *reinterpret_cast<const float4*>(&sch[r][t2]);
                acc[r] = __builtin_amdgcn_fdot2(__builtin_bit_cast(h2, raw.x), w0, acc[r], false);
                acc[r] = __builtin_amdgcn_fdot2(__builtin_bit_cast(h2, raw.y), w1, acc[r], false);
                acc[r] = __builtin_amdgcn_fdot2(__builtin_bit_cast(h2, raw.z), w2, acc[r], false);
                acc[r] = __builtin_amdgcn_fdot2(__builtin_bit_cast(h2, raw.w), w3, acc[r], false);
            }
        }
#pragma unroll
        for (int r = 0; r < 8; ++r) {
            out[(size_t)(r0 + r) * OUTD + j] = fmaxf(acc[r], 0.f);
        }
    }
}

extern "C" void kernel_launch(void* const* d_in, const int* in_sizes, int n_in,
                              void* d_out, int out_size, void* d_ws, size_t ws_size,
                              hipStream_t stream) {
    const float* x  = (const float*)d_in[0];
    const float* lw = (const float*)d_in[1];
    const float* lb = (const float*)d_in[2];
    const float* fw = (const float*)d_in[3];
    const float* fb = (const float*)d_in[4];
    float* out = (float*)d_out;

    float* pooled = (float*)d_ws;
    const size_t POOLED_B = (size_t)BATCH * COMB * 4;
    const size_t NEEDED   = POOLED_B + (size_t)(LW_PAIRS + FW_PAIRS) * 4;

    dwt_pool_kernel<<<BATCH * 2, NTHR, 0, stream>>>(x, pooled);

    if (ws_size >= NEEDED) {
        h2* lwh = (h2*)((char*)d_ws + POOLED_B);
        h2* fwh = (h2*)((char*)d_ws + POOLED_B + (size_t)LW_PAIRS * 4);
        pack_w<<<(LW_PAIRS + FW_PAIRS + 255) / 256, 256, 0, stream>>>(lw, fw, lwh, fwh);
        mlp_kernel<<<BATCH / 8, 1024, 0, stream>>>(pooled, lwh, lb, fwh, fb, out);
    } else {
        mlp_kernel_fb<<<BATCH / 8, 512, 0, stream>>>(pooled, lw, lb, fw, fb, out);
    }
}